// Round 20
// baseline (420.967 us; speedup 1.0000x reference)
//
#include <hip/hip_runtime.h>

// Problem constants
#define TT 16
#define NN 50000
#define FF 64
#define EE 131072
#define NEDGE (TT*EE)          // 2097152
#define RPB 32                 // rows per range
#define NRANGE ((NN + RPB - 1) / RPB)   // 1563
#define NSUB 8                 // XCD-proxy sub-buckets per range
#define BCAP 256               // capacity per sub-bucket (mean 168, +6.8 sigma)
#define NBUCK (NRANGE*NSUB)    // 12504
#define SLOTS (NSUB*BCAP)      // 2048 int2 slots per range region
#define EMAX 1791              // sorted-edge capacity (slots before tail header)
#define TAILI (EMAX*2)         // int index of 513-int offset header in region
#define NTILES 6250            // 8-node k1 tiles (6250*8 = 50000 exact)
#define K1BLKS 1563            // k1 blocks, 4 tiles each
#define APPBLKS (NEDGE/256)    // 8192 append blocks

typedef __attribute__((ext_vector_type(8))) short bf16x8;
typedef __attribute__((ext_vector_type(4))) short bf16x4;
typedef __attribute__((ext_vector_type(4))) float f32x4;
typedef __attribute__((ext_vector_type(2))) int   i32x2;
typedef __attribute__((ext_vector_type(2))) unsigned u32x2;

// round-half-up f32->bf16 pair pack: 2 v_add + 1 v_perm. <=0.5 ulp, unbiased.
__device__ __forceinline__ unsigned pack2bf(float a, float b) {
    unsigned ua = __float_as_uint(a) + 0x8000u;
    unsigned ub = __float_as_uint(b) + 0x8000u;
    return __builtin_amdgcn_perm(ub, ua, 0x07060302u);
}
__device__ __forceinline__ float lo16f(unsigned u) { return __uint_as_float(u << 16); }
__device__ __forceinline__ float hi16f(unsigned u) { return __uint_as_float(u & 0xFFFF0000u); }

union U8 { unsigned u[4]; bf16x8 v; };
union U4 { unsigned u[2]; bf16x4 v; };

// K=16 bf16 MFMA. A: lane holds A[m=lane&15][k=(lane>>4)*4+j];
// B: B[k=(lane>>4)*4+j][n=lane&15]; C/D: row=(lane>>4)*4+reg, col=lane&15.
__device__ __forceinline__ f32x4 mfma16x16x16bf16(bf16x4 a, bf16x4 b, f32x4 c) {
#if __has_builtin(__builtin_amdgcn_mfma_f32_16x16x16bf16_1k)
    return __builtin_amdgcn_mfma_f32_16x16x16bf16_1k(a, b, c, 0, 0, 0);
#elif __has_builtin(__builtin_amdgcn_mfma_f32_16x16x16_bf16)
    return __builtin_amdgcn_mfma_f32_16x16x16_bf16(a, b, c, 0, 0, 0);
#else
    f32x4 d;
    asm volatile("v_mfma_f32_16x16x16_bf16 %0, %1, %2, %3\n\ts_nop 7\n\ts_nop 7"
                 : "=&v"(d) : "v"(a), "v"(b), "v"(c));
    return d;
#endif
}

// ---------------------------------------------------------------------------
// Fused dispatch (exact r18 structure, best total 329us): blocks [0,K1BLKS) =
// k1 with LDS-staged x; rest = append (1 edge/thread — r19's 4-edge variant
// regressed). k1 body unchanged.
// ---------------------------------------------------------------------------
__global__ void k1_append(
    const float* __restrict__ x, const float* __restrict__ M,
    const float* __restrict__ W, unsigned short* __restrict__ Yt,
    const int* __restrict__ rows, const int* __restrict__ cols,
    const float* __restrict__ vals, int* __restrict__ bcnt,
    i32x2* __restrict__ btmp)
{
    __shared__ __align__(16) char lds[2][16384];

    if (blockIdx.x < K1BLKS) {
        const int tid  = threadIdx.x;
        const int wid  = tid >> 6;
        const int lane = tid & 63;
        const int col  = lane & 15;   // MFMA m/n index
        const int grp  = lane >> 4;   // MFMA k-group

        // W as B-frags for 16x16x32: lane holds B[k=q*32+grp*8+j][n=t*16+col]
        bf16x8 bw[2][4];
#pragma unroll
        for (int q = 0; q < 2; ++q)
#pragma unroll
            for (int t = 0; t < 4; ++t) {
                U8 w8;
#pragma unroll
                for (int p = 0; p < 4; ++p)
                    w8.u[p] = pack2bf(W[(q*32 + grp*8 + 2*p)*FF + t*16 + col],
                                      W[(q*32 + grp*8 + 2*p + 1)*FF + t*16 + col]);
                bw[q][t] = w8.v;
            }

        // M fragment: element j = M[col][grp*4+j] (B-frag of mix MFMA = M^T)
        U4 m4;
        m4.u[0] = pack2bf(M[col*16 + grp*4 + 0], M[col*16 + grp*4 + 1]);
        m4.u[1] = pack2bf(M[col*16 + grp*4 + 2], M[col*16 + grp*4 + 3]);
        const bf16x4 mf = m4.v;
        const f32x4 zero = {0.f, 0.f, 0.f, 0.f};

        // stage: wave stages slices s=wid*4..+3 of an 8-node tile.
        // LDS layout [s][node][fi] bf16, slice stride 1024B, swz ^((s&7)<<4).
#define STAGE(tt, buf)                                                        \
        {                                                                     \
            const int nb_ = (tt)*8;                                           \
            char* L_ = lds[buf];                                              \
            _Pragma("unroll")                                                 \
            for (int q = 0; q < 4; ++q) {                                     \
                const int s_ = wid*4 + q;                                     \
                const float* src_ = x + (size_t)s_*NN*FF + (size_t)nb_*FF + lane*8; \
                float4 lo_ = *reinterpret_cast<const float4*>(src_);          \
                float4 hi_ = *reinterpret_cast<const float4*>(src_ + 4);      \
                U8 pk_;                                                       \
                pk_.u[0] = pack2bf(lo_.x, lo_.y); pk_.u[1] = pack2bf(lo_.z, lo_.w); \
                pk_.u[2] = pack2bf(hi_.x, hi_.y); pk_.u[3] = pack2bf(hi_.z, hi_.w); \
                const int byte_ = (s_*1024 + lane*16) ^ ((s_ & 7) << 4);      \
                *reinterpret_cast<bf16x8*>(L_ + byte_) = pk_.v;               \
            }                                                                 \
        }

        const int t0 = blockIdx.x*4;
        if (t0 < NTILES) STAGE(t0, 0)

#pragma unroll
        for (int i = 0; i < 4; ++i) {
            const int t = t0 + i;
            if (t >= NTILES) break;
            __syncthreads();
            if (i + 1 < 4 && t + 1 < NTILES) STAGE(t + 1, (i + 1) & 1)

            const char* L = lds[i & 1];
#pragma unroll
            for (int h = 0; h < 2; ++h) {
                const int nloc = wid*2 + h;
                const int node = t*8 + nloc;
                const int base = col*1024 + nloc*128;
                const int sw = (col & 7) << 4;
                bf16x8 a0 = *reinterpret_cast<const bf16x8*>(L + ((base + grp*16) ^ sw));
                bf16x8 a1 = *reinterpret_cast<const bf16x8*>(L + ((base + 64 + grp*16) ^ sw));

                f32x4 acc[4];
#pragma unroll
                for (int t2 = 0; t2 < 4; ++t2) acc[t2] = zero;
#pragma unroll
                for (int t2 = 0; t2 < 4; ++t2)
                    acc[t2] = __builtin_amdgcn_mfma_f32_16x16x32_bf16(a0, bw[0][t2], acc[t2], 0, 0, 0);
#pragma unroll
                for (int t2 = 0; t2 < 4; ++t2)
                    acc[t2] = __builtin_amdgcn_mfma_f32_16x16x32_bf16(a1, bw[1][t2], acc[t2], 0, 0, 0);

#pragma unroll
                for (int t2 = 0; t2 < 4; ++t2) {
                    U4 pb;
                    pb.u[0] = pack2bf(acc[t2][0], acc[t2][1]);
                    pb.u[1] = pack2bf(acc[t2][2], acc[t2][3]);
                    f32x4 y = mfma16x16x16bf16(pb.v, mf, zero);
                    u32x2 st;
                    st[0] = pack2bf(y[0], y[1]);
                    st[1] = pack2bf(y[2], y[3]);
                    *reinterpret_cast<u32x2*>(Yt + (size_t)node*1024 + col*64 + t2*16 + grp*4) = st;
                }
            }
        }
#undef STAGE
    } else {
        // ================= append =================
        const int i = (blockIdx.x - K1BLKS)*256 + threadIdx.x;   // 0..NEDGE-1
        const int r = rows[i];
        const int j = i >> 17;                        // EE = 2^17
        const int b = (r >> 5)*NSUB + (blockIdx.x & 7);
        const int pos = atomicAdd(&bcnt[b], 1);
        if (pos < BCAP) {
            i32x2 e;
            e[0] = cols[i] | (((r & 31)*16 + j) << 16);
            e[1] = __float_as_int(vals[i]);
            btmp[(size_t)b*BCAP + pos] = e;
        }
    }
}

// ---------------------------------------------------------------------------
// sort: block per range. Counting-sort the range's edges in LDS, write back
// IN PLACE (linear, coalesced), sorted by key=(rl,j), + 513-int offset header.
// ---------------------------------------------------------------------------
__global__ __launch_bounds__(256) void sort_kernel(
    const int* __restrict__ bcnt, i32x2* __restrict__ btmp)
{
    __shared__ i32x2 sbuf[SLOTS];     // 16KB
    __shared__ int scnt[512], soff[512], scur[512], pscan[256];

    const int tid = threadIdx.x;
    const int blk = blockIdx.x;
    i32x2* region = btmp + (size_t)blk*SLOTS;

    scnt[tid] = 0; scnt[tid + 256] = 0;
    __syncthreads();

    int bc[NSUB]; i32x2 ent[NSUB];
#pragma unroll
    for (int s = 0; s < NSUB; ++s) {
        int c = bcnt[blk*NSUB + s];
        bc[s] = c < BCAP ? c : BCAP;
    }
#pragma unroll
    for (int s = 0; s < NSUB; ++s)
        if (tid < bc[s]) {
            ent[s] = region[s*BCAP + tid];
            atomicAdd(&scnt[((unsigned)ent[s][0]) >> 16], 1);
        }
    __syncthreads();

    const int a0 = scnt[2*tid], a1 = scnt[2*tid + 1];
    const int ps = a0 + a1;
    pscan[tid] = ps;
    __syncthreads();
    for (int o = 1; o < 256; o <<= 1) {
        int v = (tid >= o) ? pscan[tid - o] : 0;
        __syncthreads();
        pscan[tid] += v;
        __syncthreads();
    }
    const int excl = pscan[tid] - ps;
    soff[2*tid] = excl;      soff[2*tid + 1] = excl + a0;
    scur[2*tid] = excl;      scur[2*tid + 1] = excl + a0;
    __syncthreads();

#pragma unroll
    for (int s = 0; s < NSUB; ++s)
        if (tid < bc[s]) {
            const int key = ((unsigned)ent[s][0]) >> 16;
            const int pos = atomicAdd(&scur[key], 1);
            i32x2 se; se[0] = ent[s][0] & 0xFFFF; se[1] = ent[s][1];
            sbuf[pos] = se;
        }
    __syncthreads();

    const int total = soff[511] + scnt[511];
    const int lim = total < EMAX ? total : EMAX;
    for (int i = tid; i < lim; i += 256) region[i] = sbuf[i];
    int* tail = (int*)region + TAILI;
    tail[tid] = soff[tid];
    tail[tid + 256] = soff[tid + 256];
    if (tid == 0) tail[512] = lim;
}

// ---------------------------------------------------------------------------
// k2 with SEQUENTIAL k-blocking: two dispatches, k in [KLO, KLO+8). Each pass
// gathers only 1KB of each node's 2KB Yt block -> 51MB working set stays
// L3-resident despite the out-write stream (r12: full-range pass re-fetched
// Yt ~3x, FETCH 368MB). Sequential (stream-ordered), NOT concurrent — r10's
// concurrent split doubled live gather streams and thrashed (578MB).
// Wave structure identical to the proven r12 kernel; acc halves to 8xf32x4.
// ---------------------------------------------------------------------------
template<int J, int KLO>
__device__ __forceinline__ void k2_batch(int p0, int nj, int sbase, int esub, int fq,
    const i32x2* eb, const unsigned short* __restrict__ Yt,
    const float* __restrict__ M, f32x4* acc)
{
    const int p = p0 + esub;
    const bool act = p < nj;
    const int li = act ? (sbase + p) : 0;
    const i32x2 ent = eb[li];                 // LDS read
    const float v = act ? __int_as_float(ent[1]) : 0.f;
    const int node = act ? ent[0] : 0;        // masked lanes read Yt[0]
    const unsigned short* yb = Yt + (size_t)node*1024 + fq*4;
#pragma unroll
    for (int d = 0; d < 3; ++d) {
        if (J + d >= KLO && J + d < KLO + 8 && J + d < 16) {
            const int K = J + d;
            const u32x2 uv = *reinterpret_cast<const u32x2*>(yb + K*64);
            const float wv = M[K*16 + J] * v;
            acc[K - KLO][0] = fmaf(wv, lo16f(uv[0]), acc[K - KLO][0]);
            acc[K - KLO][1] = fmaf(wv, hi16f(uv[0]), acc[K - KLO][1]);
            acc[K - KLO][2] = fmaf(wv, lo16f(uv[1]), acc[K - KLO][2]);
            acc[K - KLO][3] = fmaf(wv, hi16f(uv[1]), acc[K - KLO][3]);
        }
    }
}

template<int KLO>
__global__ __launch_bounds__(256) void k2_half(
    const unsigned short* __restrict__ Yt, const float* __restrict__ M,
    const i32x2* __restrict__ btmp, float* __restrict__ out)
{
    constexpr int JLO = (KLO == 0) ? 0 : 6;
    constexpr int JHI = (KLO == 0) ? 7 : 15;
    __shared__ i32x2 ebuf[4][96];
    const int tid  = threadIdx.x;
    const int wid  = tid >> 6;
    const int lane = tid & 63;
    const int esub = lane >> 4;   // edge slot 0..3
    const int fq   = lane & 15;   // feature quad
    const int r   = blockIdx.x*4 + wid;   // 12500*4 = 50000 exact
    const int blk = r >> 5;
    const int rl  = r & 31;

    const i32x2* region = btmp + (size_t)blk*SLOTS;
    const int* tail = (const int*)region + TAILI;
    int o_l = 0;
    if (lane < 17) o_l = tail[rl*16 + lane];
    int off[17];
#pragma unroll
    for (int j = 0; j < 17; ++j) off[j] = __builtin_amdgcn_readlane(o_l, j);
    int ntot = off[JHI + 1] - off[JLO];
    ntot = ntot < 96 ? ntot : 96;
    const i32x2* rowsrc = region + off[JLO];

    i32x2* eb = ebuf[wid];
    if (lane < ntot)      eb[lane]      = rowsrc[lane];
    if (lane + 64 < ntot) eb[lane + 64] = rowsrc[lane + 64];

    int c[16], sb[16];
#pragma unroll
    for (int j = JLO; j <= JHI; ++j) {
        c[j]  = off[j+1] - off[j];
        sb[j] = off[j] - off[JLO];
    }

    f32x4 acc[8];
#pragma unroll
    for (int k = 0; k < 8; ++k) acc[k] = (f32x4){0.f, 0.f, 0.f, 0.f};

#define P1(J) k2_batch<J,KLO>(0, c[J], sb[J], esub, fq, eb, Yt, M, acc);
#define P2(J) for (int p0 = 4; p0 < c[J]; p0 += 4) \
        k2_batch<J,KLO>(p0, c[J], sb[J], esub, fq, eb, Yt, M, acc);
    if constexpr (KLO == 0) {
        P1(0) P1(1) P1(2) P1(3) P1(4) P1(5) P1(6) P1(7)
        P2(0) P2(1) P2(2) P2(3) P2(4) P2(5) P2(6) P2(7)
    } else {
        P1(6) P1(7) P1(8) P1(9) P1(10) P1(11) P1(12) P1(13) P1(14) P1(15)
        P2(6) P2(7) P2(8) P2(9) P2(10) P2(11) P2(12) P2(13) P2(14) P2(15)
    }
#undef P1
#undef P2

#pragma unroll
    for (int k = 0; k < 8; ++k) {
#pragma unroll
        for (int u = 0; u < 4; ++u) {
            acc[k][u] += __shfl_xor(acc[k][u], 16);
            acc[k][u] += __shfl_xor(acc[k][u], 32);
        }
    }
    if (esub == 0) {
#pragma unroll
        for (int k = 0; k < 8; ++k) {
            *reinterpret_cast<f32x4*>(out + ((size_t)(KLO + k)*NN + r)*FF + fq*4) = acc[k];
        }
    }
}

// ---------------------------------------------------------------------------
extern "C" void kernel_launch(void* const* d_in, const int* in_sizes, int n_in,
                              void* d_out, int out_size, void* d_ws, size_t ws_size,
                              hipStream_t stream) {
    (void)in_sizes; (void)n_in; (void)out_size; (void)ws_size;
    const float* x     = (const float*)d_in[0];
    const float* M     = (const float*)d_in[1];
    const float* avals = (const float*)d_in[2];
    const float* W     = (const float*)d_in[3];
    const int*   arows = (const int*)d_in[4];
    const int*   acols = (const int*)d_in[5];
    float* out = (float*)d_out;

    // workspace carve (~128.1 MB total)
    char* ws = (char*)d_ws;
    size_t o = 0;
    unsigned short* Yt = (unsigned short*)(ws + o); o += (size_t)TT*NN*FF*2;  // 102.4 MB
    o = (o + 255) & ~(size_t)255;
    int* bcnt = (int*)(ws + o); o += (size_t)NBUCK*4;  o = (o + 255) & ~(size_t)255;
    i32x2* btmp = (i32x2*)(ws + o);                    // 12504*2048*8 = 25.6 MB

    (void)hipMemsetAsync(bcnt, 0, (size_t)NBUCK*4, stream);
    hipLaunchKernelGGL(k1_append, dim3(K1BLKS + APPBLKS), dim3(256), 0, stream,
                       x, M, W, Yt, arows, acols, avals, bcnt, btmp);
    hipLaunchKernelGGL(sort_kernel, dim3(NRANGE), dim3(256), 0, stream, bcnt, btmp);
    hipLaunchKernelGGL(k2_half<0>, dim3(12500), dim3(256), 0, stream, Yt, M, btmp, out);
    hipLaunchKernelGGL(k2_half<8>, dim3(12500), dim3(256), 0, stream, Yt, M, btmp, out);
}

// Round 21
// 331.479 us; speedup vs baseline: 1.2700x; 1.2700x over previous
//
#include <hip/hip_runtime.h>

// Problem constants
#define TT 16
#define NN 50000
#define FF 64
#define EE 131072
#define NEDGE (TT*EE)          // 2097152
#define RPB 32                 // rows per range
#define NRANGE ((NN + RPB - 1) / RPB)   // 1563
#define NSUB 8                 // XCD-proxy sub-buckets per range
#define BCAP 256               // capacity per sub-bucket (mean 168, +6.8 sigma)
#define NBUCK (NRANGE*NSUB)    // 12504
#define SLOTS (NSUB*BCAP)      // 2048 int2 slots per range region
#define EMAX 1791              // sorted-edge capacity (slots before tail header)
#define TAILI (EMAX*2)         // int index of 513-int offset header in region
#define NTILES 6250            // 8-node k1 tiles (6250*8 = 50000 exact)
#define K1BLKS 1563            // k1 blocks, 4 tiles each (6252 >= 6250)
#define APPBLKS (NEDGE/256)    // 8192 append blocks

typedef __attribute__((ext_vector_type(8))) short bf16x8;
typedef __attribute__((ext_vector_type(4))) short bf16x4;
typedef __attribute__((ext_vector_type(4))) float f32x4;
typedef __attribute__((ext_vector_type(2))) int   i32x2;
typedef __attribute__((ext_vector_type(2))) unsigned u32x2;

// round-half-up f32->bf16 pair pack: 2 v_add + 1 v_perm. <=0.5 ulp, unbiased.
__device__ __forceinline__ unsigned pack2bf(float a, float b) {
    unsigned ua = __float_as_uint(a) + 0x8000u;
    unsigned ub = __float_as_uint(b) + 0x8000u;
    return __builtin_amdgcn_perm(ub, ua, 0x07060302u);
}
__device__ __forceinline__ float lo16f(unsigned u) { return __uint_as_float(u << 16); }
__device__ __forceinline__ float hi16f(unsigned u) { return __uint_as_float(u & 0xFFFF0000u); }

union U8 { unsigned u[4]; bf16x8 v; };
union U4 { unsigned u[2]; bf16x4 v; };

// K=16 bf16 MFMA. A: lane holds A[m=lane&15][k=(lane>>4)*4+j];
// B: B[k=(lane>>4)*4+j][n=lane&15]; C/D: row=(lane>>4)*4+reg, col=lane&15.
__device__ __forceinline__ f32x4 mfma16x16x16bf16(bf16x4 a, bf16x4 b, f32x4 c) {
#if __has_builtin(__builtin_amdgcn_mfma_f32_16x16x16bf16_1k)
    return __builtin_amdgcn_mfma_f32_16x16x16bf16_1k(a, b, c, 0, 0, 0);
#elif __has_builtin(__builtin_amdgcn_mfma_f32_16x16x16_bf16)
    return __builtin_amdgcn_mfma_f32_16x16x16_bf16(a, b, c, 0, 0, 0);
#else
    f32x4 d;
    asm volatile("v_mfma_f32_16x16x16_bf16 %0, %1, %2, %3\n\ts_nop 7\n\ts_nop 7"
                 : "=&v"(d) : "v"(a), "v"(b), "v"(c));
    return d;
#endif
}

// ---------------------------------------------------------------------------
// Fused dispatch (r18 configuration — verified best, 329us total):
// blocks [0,K1BLKS) = k1 with LDS-staged x (double-buffered); rest = append
// (1 edge/thread). k2 single-pass (r20: sequential k-blocking halves
// arithmetic intensity per gather and regressed; r10: concurrent split
// thrashed L3 — 166us is k2's practical floor).
// ---------------------------------------------------------------------------
__global__ void k1_append(
    const float* __restrict__ x, const float* __restrict__ M,
    const float* __restrict__ W, unsigned short* __restrict__ Yt,
    const int* __restrict__ rows, const int* __restrict__ cols,
    const float* __restrict__ vals, int* __restrict__ bcnt,
    i32x2* __restrict__ btmp)
{
    __shared__ __align__(16) char lds[2][16384];

    if (blockIdx.x < K1BLKS) {
        const int tid  = threadIdx.x;
        const int wid  = tid >> 6;
        const int lane = tid & 63;
        const int col  = lane & 15;   // MFMA m/n index
        const int grp  = lane >> 4;   // MFMA k-group

        // W as B-frags for 16x16x32: lane holds B[k=q*32+grp*8+j][n=t*16+col]
        bf16x8 bw[2][4];
#pragma unroll
        for (int q = 0; q < 2; ++q)
#pragma unroll
            for (int t = 0; t < 4; ++t) {
                U8 w8;
#pragma unroll
                for (int p = 0; p < 4; ++p)
                    w8.u[p] = pack2bf(W[(q*32 + grp*8 + 2*p)*FF + t*16 + col],
                                      W[(q*32 + grp*8 + 2*p + 1)*FF + t*16 + col]);
                bw[q][t] = w8.v;
            }

        // M fragment: element j = M[col][grp*4+j] (B-frag of mix MFMA = M^T)
        U4 m4;
        m4.u[0] = pack2bf(M[col*16 + grp*4 + 0], M[col*16 + grp*4 + 1]);
        m4.u[1] = pack2bf(M[col*16 + grp*4 + 2], M[col*16 + grp*4 + 3]);
        const bf16x4 mf = m4.v;
        const f32x4 zero = {0.f, 0.f, 0.f, 0.f};

        // stage: wave stages slices s=wid*4..+3 of an 8-node tile.
        // LDS layout [s][node][fi] bf16, slice stride 1024B, swz ^((s&7)<<4).
#define STAGE(tt, buf)                                                        \
        {                                                                     \
            const int nb_ = (tt)*8;                                           \
            char* L_ = lds[buf];                                              \
            _Pragma("unroll")                                                 \
            for (int q = 0; q < 4; ++q) {                                     \
                const int s_ = wid*4 + q;                                     \
                const float* src_ = x + (size_t)s_*NN*FF + (size_t)nb_*FF + lane*8; \
                float4 lo_ = *reinterpret_cast<const float4*>(src_);          \
                float4 hi_ = *reinterpret_cast<const float4*>(src_ + 4);      \
                U8 pk_;                                                       \
                pk_.u[0] = pack2bf(lo_.x, lo_.y); pk_.u[1] = pack2bf(lo_.z, lo_.w); \
                pk_.u[2] = pack2bf(hi_.x, hi_.y); pk_.u[3] = pack2bf(hi_.z, hi_.w); \
                const int byte_ = (s_*1024 + lane*16) ^ ((s_ & 7) << 4);      \
                *reinterpret_cast<bf16x8*>(L_ + byte_) = pk_.v;               \
            }                                                                 \
        }

        const int t0 = blockIdx.x*4;
        if (t0 < NTILES) STAGE(t0, 0)

#pragma unroll
        for (int i = 0; i < 4; ++i) {
            const int t = t0 + i;
            if (t >= NTILES) break;
            __syncthreads();
            if (i + 1 < 4 && t + 1 < NTILES) STAGE(t + 1, (i + 1) & 1)

            const char* L = lds[i & 1];
#pragma unroll
            for (int h = 0; h < 2; ++h) {
                const int nloc = wid*2 + h;
                const int node = t*8 + nloc;
                const int base = col*1024 + nloc*128;
                const int sw = (col & 7) << 4;
                bf16x8 a0 = *reinterpret_cast<const bf16x8*>(L + ((base + grp*16) ^ sw));
                bf16x8 a1 = *reinterpret_cast<const bf16x8*>(L + ((base + 64 + grp*16) ^ sw));

                f32x4 acc[4];
#pragma unroll
                for (int t2 = 0; t2 < 4; ++t2) acc[t2] = zero;
#pragma unroll
                for (int t2 = 0; t2 < 4; ++t2)
                    acc[t2] = __builtin_amdgcn_mfma_f32_16x16x32_bf16(a0, bw[0][t2], acc[t2], 0, 0, 0);
#pragma unroll
                for (int t2 = 0; t2 < 4; ++t2)
                    acc[t2] = __builtin_amdgcn_mfma_f32_16x16x32_bf16(a1, bw[1][t2], acc[t2], 0, 0, 0);

#pragma unroll
                for (int t2 = 0; t2 < 4; ++t2) {
                    U4 pb;
                    pb.u[0] = pack2bf(acc[t2][0], acc[t2][1]);
                    pb.u[1] = pack2bf(acc[t2][2], acc[t2][3]);
                    f32x4 y = mfma16x16x16bf16(pb.v, mf, zero);
                    u32x2 st;
                    st[0] = pack2bf(y[0], y[1]);
                    st[1] = pack2bf(y[2], y[3]);
                    *reinterpret_cast<u32x2*>(Yt + (size_t)node*1024 + col*64 + t2*16 + grp*4) = st;
                }
            }
        }
#undef STAGE
    } else {
        // ================= append =================
        const int i = (blockIdx.x - K1BLKS)*256 + threadIdx.x;   // 0..NEDGE-1
        const int r = rows[i];
        const int j = i >> 17;                        // EE = 2^17
        const int b = (r >> 5)*NSUB + (blockIdx.x & 7);
        const int pos = atomicAdd(&bcnt[b], 1);
        if (pos < BCAP) {
            i32x2 e;
            e[0] = cols[i] | (((r & 31)*16 + j) << 16);
            e[1] = __float_as_int(vals[i]);
            btmp[(size_t)b*BCAP + pos] = e;
        }
    }
}

// ---------------------------------------------------------------------------
// sort: block per range. Counting-sort the range's edges in LDS, write back
// IN PLACE (linear, coalesced), sorted by key=(rl,j), + 513-int offset header.
// ---------------------------------------------------------------------------
__global__ __launch_bounds__(256) void sort_kernel(
    const int* __restrict__ bcnt, i32x2* __restrict__ btmp)
{
    __shared__ i32x2 sbuf[SLOTS];     // 16KB
    __shared__ int scnt[512], soff[512], scur[512], pscan[256];

    const int tid = threadIdx.x;
    const int blk = blockIdx.x;
    i32x2* region = btmp + (size_t)blk*SLOTS;

    scnt[tid] = 0; scnt[tid + 256] = 0;
    __syncthreads();

    int bc[NSUB]; i32x2 ent[NSUB];
#pragma unroll
    for (int s = 0; s < NSUB; ++s) {
        int c = bcnt[blk*NSUB + s];
        bc[s] = c < BCAP ? c : BCAP;
    }
#pragma unroll
    for (int s = 0; s < NSUB; ++s)
        if (tid < bc[s]) {
            ent[s] = region[s*BCAP + tid];
            atomicAdd(&scnt[((unsigned)ent[s][0]) >> 16], 1);
        }
    __syncthreads();

    const int a0 = scnt[2*tid], a1 = scnt[2*tid + 1];
    const int ps = a0 + a1;
    pscan[tid] = ps;
    __syncthreads();
    for (int o = 1; o < 256; o <<= 1) {
        int v = (tid >= o) ? pscan[tid - o] : 0;
        __syncthreads();
        pscan[tid] += v;
        __syncthreads();
    }
    const int excl = pscan[tid] - ps;
    soff[2*tid] = excl;      soff[2*tid + 1] = excl + a0;
    scur[2*tid] = excl;      scur[2*tid + 1] = excl + a0;
    __syncthreads();

#pragma unroll
    for (int s = 0; s < NSUB; ++s)
        if (tid < bc[s]) {
            const int key = ((unsigned)ent[s][0]) >> 16;
            const int pos = atomicAdd(&scur[key], 1);
            i32x2 se; se[0] = ent[s][0] & 0xFFFF; se[1] = ent[s][1];
            sbuf[pos] = se;
        }
    __syncthreads();

    const int total = soff[511] + scnt[511];
    const int lim = total < EMAX ? total : EMAX;
    for (int i = tid; i < lim; i += 256) region[i] = sbuf[i];
    int* tail = (int*)region + TAILI;
    tail[tid] = soff[tid];
    tail[tid + 256] = soff[tid + 256];
    if (tid == 0) tail[512] = lim;
}

// ---------------------------------------------------------------------------
// k2_gather: one wave per row (proven ~166us; practical floor per r10/r20
// k-split failures). acc[16], plain loads, single pass.
// ---------------------------------------------------------------------------
template<int J>
__device__ __forceinline__ void k2_batch(int p0, int nj, int sbase, int esub, int fq,
    const i32x2* eb, const unsigned short* __restrict__ Yt,
    const float* __restrict__ M, f32x4* acc)
{
    const int p = p0 + esub;
    const bool act = p < nj;
    const int li = act ? (sbase + p) : 0;
    const i32x2 ent = eb[li];                 // LDS read
    const float v = act ? __int_as_float(ent[1]) : 0.f;
    const int node = act ? ent[0] : 0;        // masked lanes read Yt[0]
    const unsigned short* yb = Yt + (size_t)node*1024 + J*64 + fq*4;
    {
        const u32x2 uv = *reinterpret_cast<const u32x2*>(yb);
        const float wv = M[J*17] * v;
        acc[J][0] = fmaf(wv, lo16f(uv[0]), acc[J][0]);
        acc[J][1] = fmaf(wv, hi16f(uv[0]), acc[J][1]);
        acc[J][2] = fmaf(wv, lo16f(uv[1]), acc[J][2]);
        acc[J][3] = fmaf(wv, hi16f(uv[1]), acc[J][3]);
    }
    if constexpr (J < 15) {
        const u32x2 uv = *reinterpret_cast<const u32x2*>(yb + 64);
        const float wv = M[J*17 + 16] * v;
        acc[J+1][0] = fmaf(wv, lo16f(uv[0]), acc[J+1][0]);
        acc[J+1][1] = fmaf(wv, hi16f(uv[0]), acc[J+1][1]);
        acc[J+1][2] = fmaf(wv, lo16f(uv[1]), acc[J+1][2]);
        acc[J+1][3] = fmaf(wv, hi16f(uv[1]), acc[J+1][3]);
    }
    if constexpr (J < 14) {
        const u32x2 uv = *reinterpret_cast<const u32x2*>(yb + 128);
        const float wv = M[J*17 + 32] * v;
        acc[J+2][0] = fmaf(wv, lo16f(uv[0]), acc[J+2][0]);
        acc[J+2][1] = fmaf(wv, hi16f(uv[0]), acc[J+2][1]);
        acc[J+2][2] = fmaf(wv, lo16f(uv[1]), acc[J+2][2]);
        acc[J+2][3] = fmaf(wv, hi16f(uv[1]), acc[J+2][3]);
    }
}

__global__ __launch_bounds__(256) void k2_gather(
    const unsigned short* __restrict__ Yt, const float* __restrict__ M,
    const i32x2* __restrict__ btmp, float* __restrict__ out)
{
    __shared__ i32x2 ebuf[4][128];
    const int tid  = threadIdx.x;
    const int wid  = tid >> 6;
    const int lane = tid & 63;
    const int esub = lane >> 4;   // edge slot 0..3
    const int fq   = lane & 15;   // feature quad
    const int r   = blockIdx.x*4 + wid;   // 12500*4 = 50000 exact
    const int blk = r >> 5;
    const int rl  = r & 31;

    const i32x2* region = btmp + (size_t)blk*SLOTS;
    const int* tail = (const int*)region + TAILI;
    int o_l = 0;
    if (lane < 17) o_l = tail[rl*16 + lane];
    int off[17];
#pragma unroll
    for (int j = 0; j < 17; ++j) off[j] = __builtin_amdgcn_readlane(o_l, j);
    int ntot = off[16] - off[0];
    ntot = ntot < 128 ? ntot : 128;
    const i32x2* rowsrc = region + off[0];

    i32x2* eb = ebuf[wid];
    if (lane < ntot)      eb[lane]      = rowsrc[lane];
    if (lane + 64 < ntot) eb[lane + 64] = rowsrc[lane + 64];

    int c[16], sb[16];
#pragma unroll
    for (int j = 0; j < 16; ++j) {
        c[j]  = off[j+1] - off[j];
        sb[j] = off[j] - off[0];
    }

    f32x4 acc[16];
#pragma unroll
    for (int k = 0; k < 16; ++k) acc[k] = (f32x4){0.f, 0.f, 0.f, 0.f};

    // pass 1: first batch of every section, straight-line
#define P1(J) k2_batch<J>(0, c[J], sb[J], esub, fq, eb, Yt, M, acc);
    P1(0)  P1(1)  P1(2)  P1(3)  P1(4)  P1(5)  P1(6)  P1(7)
    P1(8)  P1(9)  P1(10) P1(11) P1(12) P1(13) P1(14) P1(15)
#undef P1
    // pass 2: residual batches (usually empty)
#define P2(J) for (int p0 = 4; p0 < c[J]; p0 += 4) \
        k2_batch<J>(p0, c[J], sb[J], esub, fq, eb, Yt, M, acc);
    P2(0)  P2(1)  P2(2)  P2(3)  P2(4)  P2(5)  P2(6)  P2(7)
    P2(8)  P2(9)  P2(10) P2(11) P2(12) P2(13) P2(14) P2(15)
#undef P2

#pragma unroll
    for (int k = 0; k < 16; ++k) {
#pragma unroll
        for (int u = 0; u < 4; ++u) {
            acc[k][u] += __shfl_xor(acc[k][u], 16);
            acc[k][u] += __shfl_xor(acc[k][u], 32);
        }
    }
    if (esub == 0) {
#pragma unroll
        for (int k = 0; k < 16; ++k) {
            *reinterpret_cast<f32x4*>(out + ((size_t)k*NN + r)*FF + fq*4) = acc[k];
        }
    }
}

// ---------------------------------------------------------------------------
extern "C" void kernel_launch(void* const* d_in, const int* in_sizes, int n_in,
                              void* d_out, int out_size, void* d_ws, size_t ws_size,
                              hipStream_t stream) {
    (void)in_sizes; (void)n_in; (void)out_size; (void)ws_size;
    const float* x     = (const float*)d_in[0];
    const float* M     = (const float*)d_in[1];
    const float* avals = (const float*)d_in[2];
    const float* W     = (const float*)d_in[3];
    const int*   arows = (const int*)d_in[4];
    const int*   acols = (const int*)d_in[5];
    float* out = (float*)d_out;

    // workspace carve (~128.1 MB total)
    char* ws = (char*)d_ws;
    size_t o = 0;
    unsigned short* Yt = (unsigned short*)(ws + o); o += (size_t)TT*NN*FF*2;  // 102.4 MB
    o = (o + 255) & ~(size_t)255;
    int* bcnt = (int*)(ws + o); o += (size_t)NBUCK*4;  o = (o + 255) & ~(size_t)255;
    i32x2* btmp = (i32x2*)(ws + o);                    // 12504*2048*8 = 25.6 MB

    (void)hipMemsetAsync(bcnt, 0, (size_t)NBUCK*4, stream);
    hipLaunchKernelGGL(k1_append, dim3(K1BLKS + APPBLKS), dim3(256), 0, stream,
                       x, M, W, Yt, arows, acols, avals, bcnt, btmp);
    hipLaunchKernelGGL(sort_kernel, dim3(NRANGE), dim3(256), 0, stream, bcnt, btmp);
    hipLaunchKernelGGL(k2_gather, dim3(12500), dim3(256), 0, stream, Yt, M, btmp, out);
}

// Round 22
// 327.999 us; speedup vs baseline: 1.2834x; 1.0106x over previous
//
#include <hip/hip_runtime.h>

// Problem constants
#define TT 16
#define NN 50000
#define FF 64
#define EE 131072
#define NEDGE (TT*EE)          // 2097152
#define RPB 32                 // rows per range
#define NRANGE ((NN + RPB - 1) / RPB)   // 1563
#define NSUB 8                 // XCD-proxy sub-buckets per range
#define BCAP 256               // capacity per sub-bucket (mean 168, +6.8 sigma)
#define NBUCK (NRANGE*NSUB)    // 12504
#define SLOTS (NSUB*BCAP)      // 2048 int2 slots per range region
#define EMAX 1791              // sorted-edge capacity (slots before tail header)
#define TAILI (EMAX*2)         // int index of 513-int offset header in region
#define NTILES 6250            // 8-node k1 tiles (6250*8 = 50000 exact)
#define K1BLKS 1563            // k1 blocks, 4 tiles each (6252 >= 6250)
#define APPBLKS (NEDGE/256)    // 8192 append blocks

typedef __attribute__((ext_vector_type(8))) short bf16x8;
typedef __attribute__((ext_vector_type(4))) short bf16x4;
typedef __attribute__((ext_vector_type(4))) float f32x4;
typedef __attribute__((ext_vector_type(2))) int   i32x2;
typedef __attribute__((ext_vector_type(2))) unsigned u32x2;

// round-half-up f32->bf16 pair pack: 2 v_add + 1 v_perm. <=0.5 ulp, unbiased.
__device__ __forceinline__ unsigned pack2bf(float a, float b) {
    unsigned ua = __float_as_uint(a) + 0x8000u;
    unsigned ub = __float_as_uint(b) + 0x8000u;
    return __builtin_amdgcn_perm(ub, ua, 0x07060302u);
}
__device__ __forceinline__ float lo16f(unsigned u) { return __uint_as_float(u << 16); }
__device__ __forceinline__ float hi16f(unsigned u) { return __uint_as_float(u & 0xFFFF0000u); }

union U8 { unsigned u[4]; bf16x8 v; };
union U4 { unsigned u[2]; bf16x4 v; };

// K=16 bf16 MFMA. A: lane holds A[m=lane&15][k=(lane>>4)*4+j];
// B: B[k=(lane>>4)*4+j][n=lane&15]; C/D: row=(lane>>4)*4+reg, col=lane&15.
__device__ __forceinline__ f32x4 mfma16x16x16bf16(bf16x4 a, bf16x4 b, f32x4 c) {
#if __has_builtin(__builtin_amdgcn_mfma_f32_16x16x16bf16_1k)
    return __builtin_amdgcn_mfma_f32_16x16x16bf16_1k(a, b, c, 0, 0, 0);
#elif __has_builtin(__builtin_amdgcn_mfma_f32_16x16x16_bf16)
    return __builtin_amdgcn_mfma_f32_16x16x16_bf16(a, b, c, 0, 0, 0);
#else
    f32x4 d;
    asm volatile("v_mfma_f32_16x16x16_bf16 %0, %1, %2, %3\n\ts_nop 7\n\ts_nop 7"
                 : "=&v"(d) : "v"(a), "v"(b), "v"(c));
    return d;
#endif
}

// ---------------------------------------------------------------------------
// Fused dispatch (r18 structure, ONE change: single 16KB LDS buffer).
// r18's 32KB double-buffer reserved LDS for ALL blocks incl. the 8192
// LDS-free append blocks -> 5 blocks/CU cap -> append's atomic-latency
// stream starved of TLP (occupancy 40%). Double-buffer was proven useless
// for k1 (r18 == r19 k1-side). 16KB -> 10 blocks/CU ceiling.
// ---------------------------------------------------------------------------
__global__ void k1_append(
    const float* __restrict__ x, const float* __restrict__ M,
    const float* __restrict__ W, unsigned short* __restrict__ Yt,
    const int* __restrict__ rows, const int* __restrict__ cols,
    const float* __restrict__ vals, int* __restrict__ bcnt,
    i32x2* __restrict__ btmp)
{
    __shared__ __align__(16) char lds[16384];

    if (blockIdx.x < K1BLKS) {
        const int tid  = threadIdx.x;
        const int wid  = tid >> 6;
        const int lane = tid & 63;
        const int col  = lane & 15;   // MFMA m/n index
        const int grp  = lane >> 4;   // MFMA k-group

        // W as B-frags for 16x16x32: lane holds B[k=q*32+grp*8+j][n=t*16+col]
        bf16x8 bw[2][4];
#pragma unroll
        for (int q = 0; q < 2; ++q)
#pragma unroll
            for (int t = 0; t < 4; ++t) {
                U8 w8;
#pragma unroll
                for (int p = 0; p < 4; ++p)
                    w8.u[p] = pack2bf(W[(q*32 + grp*8 + 2*p)*FF + t*16 + col],
                                      W[(q*32 + grp*8 + 2*p + 1)*FF + t*16 + col]);
                bw[q][t] = w8.v;
            }

        // M fragment: element j = M[col][grp*4+j] (B-frag of mix MFMA = M^T)
        U4 m4;
        m4.u[0] = pack2bf(M[col*16 + grp*4 + 0], M[col*16 + grp*4 + 1]);
        m4.u[1] = pack2bf(M[col*16 + grp*4 + 2], M[col*16 + grp*4 + 3]);
        const bf16x4 mf = m4.v;
        const f32x4 zero = {0.f, 0.f, 0.f, 0.f};

        // stage: wave stages slices s=wid*4..+3 of an 8-node tile.
        // LDS layout [s][node][fi] bf16, slice stride 1024B, swz ^((s&7)<<4).
#define STAGE(tt)                                                             \
        {                                                                     \
            const int nb_ = (tt)*8;                                           \
            _Pragma("unroll")                                                 \
            for (int q = 0; q < 4; ++q) {                                     \
                const int s_ = wid*4 + q;                                     \
                const float* src_ = x + (size_t)s_*NN*FF + (size_t)nb_*FF + lane*8; \
                float4 lo_ = *reinterpret_cast<const float4*>(src_);          \
                float4 hi_ = *reinterpret_cast<const float4*>(src_ + 4);      \
                U8 pk_;                                                       \
                pk_.u[0] = pack2bf(lo_.x, lo_.y); pk_.u[1] = pack2bf(lo_.z, lo_.w); \
                pk_.u[2] = pack2bf(hi_.x, hi_.y); pk_.u[3] = pack2bf(hi_.z, hi_.w); \
                const int byte_ = (s_*1024 + lane*16) ^ ((s_ & 7) << 4);      \
                *reinterpret_cast<bf16x8*>(lds + byte_) = pk_.v;              \
            }                                                                 \
        }

        const int t0 = blockIdx.x*4;
#pragma unroll
        for (int i = 0; i < 4; ++i) {
            const int t = t0 + i;
            if (t >= NTILES) break;
            STAGE(t)
            __syncthreads();

#pragma unroll
            for (int h = 0; h < 2; ++h) {
                const int nloc = wid*2 + h;
                const int node = t*8 + nloc;
                const int base = col*1024 + nloc*128;
                const int sw = (col & 7) << 4;
                bf16x8 a0 = *reinterpret_cast<const bf16x8*>(lds + ((base + grp*16) ^ sw));
                bf16x8 a1 = *reinterpret_cast<const bf16x8*>(lds + ((base + 64 + grp*16) ^ sw));

                f32x4 acc[4];
#pragma unroll
                for (int t2 = 0; t2 < 4; ++t2) acc[t2] = zero;
#pragma unroll
                for (int t2 = 0; t2 < 4; ++t2)
                    acc[t2] = __builtin_amdgcn_mfma_f32_16x16x32_bf16(a0, bw[0][t2], acc[t2], 0, 0, 0);
#pragma unroll
                for (int t2 = 0; t2 < 4; ++t2)
                    acc[t2] = __builtin_amdgcn_mfma_f32_16x16x32_bf16(a1, bw[1][t2], acc[t2], 0, 0, 0);

#pragma unroll
                for (int t2 = 0; t2 < 4; ++t2) {
                    U4 pb;
                    pb.u[0] = pack2bf(acc[t2][0], acc[t2][1]);
                    pb.u[1] = pack2bf(acc[t2][2], acc[t2][3]);
                    f32x4 y = mfma16x16x16bf16(pb.v, mf, zero);
                    u32x2 st;
                    st[0] = pack2bf(y[0], y[1]);
                    st[1] = pack2bf(y[2], y[3]);
                    *reinterpret_cast<u32x2*>(Yt + (size_t)node*1024 + col*64 + t2*16 + grp*4) = st;
                }
            }
            __syncthreads();   // before next STAGE overwrites the buffer
        }
#undef STAGE
    } else {
        // ================= append (1 edge/thread, r18-proven) =================
        const int i = (blockIdx.x - K1BLKS)*256 + threadIdx.x;   // 0..NEDGE-1
        const int r = rows[i];
        const int j = i >> 17;                        // EE = 2^17
        const int b = (r >> 5)*NSUB + (blockIdx.x & 7);
        const int pos = atomicAdd(&bcnt[b], 1);
        if (pos < BCAP) {
            i32x2 e;
            e[0] = cols[i] | (((r & 31)*16 + j) << 16);
            e[1] = __float_as_int(vals[i]);
            btmp[(size_t)b*BCAP + pos] = e;
        }
    }
}

// ---------------------------------------------------------------------------
// sort: block per range. Counting-sort the range's edges in LDS, write back
// IN PLACE (linear, coalesced), sorted by key=(rl,j), + 513-int offset header.
// ---------------------------------------------------------------------------
__global__ __launch_bounds__(256) void sort_kernel(
    const int* __restrict__ bcnt, i32x2* __restrict__ btmp)
{
    __shared__ i32x2 sbuf[SLOTS];     // 16KB
    __shared__ int scnt[512], soff[512], scur[512], pscan[256];

    const int tid = threadIdx.x;
    const int blk = blockIdx.x;
    i32x2* region = btmp + (size_t)blk*SLOTS;

    scnt[tid] = 0; scnt[tid + 256] = 0;
    __syncthreads();

    int bc[NSUB]; i32x2 ent[NSUB];
#pragma unroll
    for (int s = 0; s < NSUB; ++s) {
        int c = bcnt[blk*NSUB + s];
        bc[s] = c < BCAP ? c : BCAP;
    }
#pragma unroll
    for (int s = 0; s < NSUB; ++s)
        if (tid < bc[s]) {
            ent[s] = region[s*BCAP + tid];
            atomicAdd(&scnt[((unsigned)ent[s][0]) >> 16], 1);
        }
    __syncthreads();

    const int a0 = scnt[2*tid], a1 = scnt[2*tid + 1];
    const int ps = a0 + a1;
    pscan[tid] = ps;
    __syncthreads();
    for (int o = 1; o < 256; o <<= 1) {
        int v = (tid >= o) ? pscan[tid - o] : 0;
        __syncthreads();
        pscan[tid] += v;
        __syncthreads();
    }
    const int excl = pscan[tid] - ps;
    soff[2*tid] = excl;      soff[2*tid + 1] = excl + a0;
    scur[2*tid] = excl;      scur[2*tid + 1] = excl + a0;
    __syncthreads();

#pragma unroll
    for (int s = 0; s < NSUB; ++s)
        if (tid < bc[s]) {
            const int key = ((unsigned)ent[s][0]) >> 16;
            const int pos = atomicAdd(&scur[key], 1);
            i32x2 se; se[0] = ent[s][0] & 0xFFFF; se[1] = ent[s][1];
            sbuf[pos] = se;
        }
    __syncthreads();

    const int total = soff[511] + scnt[511];
    const int lim = total < EMAX ? total : EMAX;
    for (int i = tid; i < lim; i += 256) region[i] = sbuf[i];
    int* tail = (int*)region + TAILI;
    tail[tid] = soff[tid];
    tail[tid + 256] = soff[tid + 256];
    if (tid == 0) tail[512] = lim;
}

// ---------------------------------------------------------------------------
// k2_gather: one wave per row (proven ~166us; practical floor per r10/r20
// k-split failures). acc[16], plain loads, single pass. Unchanged.
// ---------------------------------------------------------------------------
template<int J>
__device__ __forceinline__ void k2_batch(int p0, int nj, int sbase, int esub, int fq,
    const i32x2* eb, const unsigned short* __restrict__ Yt,
    const float* __restrict__ M, f32x4* acc)
{
    const int p = p0 + esub;
    const bool act = p < nj;
    const int li = act ? (sbase + p) : 0;
    const i32x2 ent = eb[li];                 // LDS read
    const float v = act ? __int_as_float(ent[1]) : 0.f;
    const int node = act ? ent[0] : 0;        // masked lanes read Yt[0]
    const unsigned short* yb = Yt + (size_t)node*1024 + J*64 + fq*4;
    {
        const u32x2 uv = *reinterpret_cast<const u32x2*>(yb);
        const float wv = M[J*17] * v;
        acc[J][0] = fmaf(wv, lo16f(uv[0]), acc[J][0]);
        acc[J][1] = fmaf(wv, hi16f(uv[0]), acc[J][1]);
        acc[J][2] = fmaf(wv, lo16f(uv[1]), acc[J][2]);
        acc[J][3] = fmaf(wv, hi16f(uv[1]), acc[J][3]);
    }
    if constexpr (J < 15) {
        const u32x2 uv = *reinterpret_cast<const u32x2*>(yb + 64);
        const float wv = M[J*17 + 16] * v;
        acc[J+1][0] = fmaf(wv, lo16f(uv[0]), acc[J+1][0]);
        acc[J+1][1] = fmaf(wv, hi16f(uv[0]), acc[J+1][1]);
        acc[J+1][2] = fmaf(wv, lo16f(uv[1]), acc[J+1][2]);
        acc[J+1][3] = fmaf(wv, hi16f(uv[1]), acc[J+1][3]);
    }
    if constexpr (J < 14) {
        const u32x2 uv = *reinterpret_cast<const u32x2*>(yb + 128);
        const float wv = M[J*17 + 32] * v;
        acc[J+2][0] = fmaf(wv, lo16f(uv[0]), acc[J+2][0]);
        acc[J+2][1] = fmaf(wv, hi16f(uv[0]), acc[J+2][1]);
        acc[J+2][2] = fmaf(wv, lo16f(uv[1]), acc[J+2][2]);
        acc[J+2][3] = fmaf(wv, hi16f(uv[1]), acc[J+2][3]);
    }
}

__global__ __launch_bounds__(256) void k2_gather(
    const unsigned short* __restrict__ Yt, const float* __restrict__ M,
    const i32x2* __restrict__ btmp, float* __restrict__ out)
{
    __shared__ i32x2 ebuf[4][128];
    const int tid  = threadIdx.x;
    const int wid  = tid >> 6;
    const int lane = tid & 63;
    const int esub = lane >> 4;   // edge slot 0..3
    const int fq   = lane & 15;   // feature quad
    const int r   = blockIdx.x*4 + wid;   // 12500*4 = 50000 exact
    const int blk = r >> 5;
    const int rl  = r & 31;

    const i32x2* region = btmp + (size_t)blk*SLOTS;
    const int* tail = (const int*)region + TAILI;
    int o_l = 0;
    if (lane < 17) o_l = tail[rl*16 + lane];
    int off[17];
#pragma unroll
    for (int j = 0; j < 17; ++j) off[j] = __builtin_amdgcn_readlane(o_l, j);
    int ntot = off[16] - off[0];
    ntot = ntot < 128 ? ntot : 128;
    const i32x2* rowsrc = region + off[0];

    i32x2* eb = ebuf[wid];
    if (lane < ntot)      eb[lane]      = rowsrc[lane];
    if (lane + 64 < ntot) eb[lane + 64] = rowsrc[lane + 64];

    int c[16], sb[16];
#pragma unroll
    for (int j = 0; j < 16; ++j) {
        c[j]  = off[j+1] - off[j];
        sb[j] = off[j] - off[0];
    }

    f32x4 acc[16];
#pragma unroll
    for (int k = 0; k < 16; ++k) acc[k] = (f32x4){0.f, 0.f, 0.f, 0.f};

    // pass 1: first batch of every section, straight-line
#define P1(J) k2_batch<J>(0, c[J], sb[J], esub, fq, eb, Yt, M, acc);
    P1(0)  P1(1)  P1(2)  P1(3)  P1(4)  P1(5)  P1(6)  P1(7)
    P1(8)  P1(9)  P1(10) P1(11) P1(12) P1(13) P1(14) P1(15)
#undef P1
    // pass 2: residual batches (usually empty)
#define P2(J) for (int p0 = 4; p0 < c[J]; p0 += 4) \
        k2_batch<J>(p0, c[J], sb[J], esub, fq, eb, Yt, M, acc);
    P2(0)  P2(1)  P2(2)  P2(3)  P2(4)  P2(5)  P2(6)  P2(7)
    P2(8)  P2(9)  P2(10) P2(11) P2(12) P2(13) P2(14) P2(15)
#undef P2

#pragma unroll
    for (int k = 0; k < 16; ++k) {
#pragma unroll
        for (int u = 0; u < 4; ++u) {
            acc[k][u] += __shfl_xor(acc[k][u], 16);
            acc[k][u] += __shfl_xor(acc[k][u], 32);
        }
    }
    if (esub == 0) {
#pragma unroll
        for (int k = 0; k < 16; ++k) {
            *reinterpret_cast<f32x4*>(out + ((size_t)k*NN + r)*FF + fq*4) = acc[k];
        }
    }
}

// ---------------------------------------------------------------------------
extern "C" void kernel_launch(void* const* d_in, const int* in_sizes, int n_in,
                              void* d_out, int out_size, void* d_ws, size_t ws_size,
                              hipStream_t stream) {
    (void)in_sizes; (void)n_in; (void)out_size; (void)ws_size;
    const float* x     = (const float*)d_in[0];
    const float* M     = (const float*)d_in[1];
    const float* avals = (const float*)d_in[2];
    const float* W     = (const float*)d_in[3];
    const int*   arows = (const int*)d_in[4];
    const int*   acols = (const int*)d_in[5];
    float* out = (float*)d_out;

    // workspace carve (~128.1 MB total)
    char* ws = (char*)d_ws;
    size_t o = 0;
    unsigned short* Yt = (unsigned short*)(ws + o); o += (size_t)TT*NN*FF*2;  // 102.4 MB
    o = (o + 255) & ~(size_t)255;
    int* bcnt = (int*)(ws + o); o += (size_t)NBUCK*4;  o = (o + 255) & ~(size_t)255;
    i32x2* btmp = (i32x2*)(ws + o);                    // 12504*2048*8 = 25.6 MB

    (void)hipMemsetAsync(bcnt, 0, (size_t)NBUCK*4, stream);
    hipLaunchKernelGGL(k1_append, dim3(K1BLKS + APPBLKS), dim3(256), 0, stream,
                       x, M, W, Yt, arows, acols, avals, bcnt, btmp);
    hipLaunchKernelGGL(sort_kernel, dim3(NRANGE), dim3(256), 0, stream, bcnt, btmp);
    hipLaunchKernelGGL(k2_gather, dim3(12500), dim3(256), 0, stream, Yt, M, btmp, out);
}

// Round 23
// 322.977 us; speedup vs baseline: 1.3034x; 1.0155x over previous
//
#include <hip/hip_runtime.h>

// Problem constants
#define TT 16
#define NN 50000
#define FF 64
#define EE 131072
#define NEDGE (TT*EE)          // 2097152
#define RPB 32                 // rows per range
#define NRANGE ((NN + RPB - 1) / RPB)   // 1563
#define NSUB 8                 // XCD-proxy sub-buckets per range
#define BCAP 256               // capacity per sub-bucket (mean 168, +6.8 sigma)
#define NBUCK (NRANGE*NSUB)    // 12504
#define SLOTS (NSUB*BCAP)      // 2048 int2 slots per range region
#define EMAX 1791              // sorted-edge capacity (slots before tail header)
#define TAILI (EMAX*2)         // int index of 513-int offset header in region
#define NTILES 6250            // 8-node k1 tiles (6250*8 = 50000 exact)
#define K1BLKS 1563            // k1 blocks, 4 tiles each (6252 >= 6250)
#define APPBLKS (NEDGE/256)    // 8192 append blocks

typedef __attribute__((ext_vector_type(8))) short bf16x8;
typedef __attribute__((ext_vector_type(4))) short bf16x4;
typedef __attribute__((ext_vector_type(4))) float f32x4;
typedef __attribute__((ext_vector_type(2))) int   i32x2;
typedef __attribute__((ext_vector_type(2))) unsigned u32x2;

// round-half-up f32->bf16 pair pack: 2 v_add + 1 v_perm. <=0.5 ulp, unbiased.
__device__ __forceinline__ unsigned pack2bf(float a, float b) {
    unsigned ua = __float_as_uint(a) + 0x8000u;
    unsigned ub = __float_as_uint(b) + 0x8000u;
    return __builtin_amdgcn_perm(ub, ua, 0x07060302u);
}
__device__ __forceinline__ float lo16f(unsigned u) { return __uint_as_float(u << 16); }
__device__ __forceinline__ float hi16f(unsigned u) { return __uint_as_float(u & 0xFFFF0000u); }

union U8 { unsigned u[4]; bf16x8 v; };
union U4 { unsigned u[2]; bf16x4 v; };

// K=16 bf16 MFMA. A: lane holds A[m=lane&15][k=(lane>>4)*4+j];
// B: B[k=(lane>>4)*4+j][n=lane&15]; C/D: row=(lane>>4)*4+reg, col=lane&15.
__device__ __forceinline__ f32x4 mfma16x16x16bf16(bf16x4 a, bf16x4 b, f32x4 c) {
#if __has_builtin(__builtin_amdgcn_mfma_f32_16x16x16bf16_1k)
    return __builtin_amdgcn_mfma_f32_16x16x16bf16_1k(a, b, c, 0, 0, 0);
#elif __has_builtin(__builtin_amdgcn_mfma_f32_16x16x16_bf16)
    return __builtin_amdgcn_mfma_f32_16x16x16_bf16(a, b, c, 0, 0, 0);
#else
    f32x4 d;
    asm volatile("v_mfma_f32_16x16x16_bf16 %0, %1, %2, %3\n\ts_nop 7\n\ts_nop 7"
                 : "=&v"(d) : "v"(a), "v"(b), "v"(c));
    return d;
#endif
}

// ---------------------------------------------------------------------------
// Fused dispatch (r22 structure, ONE change: Yt stores routed through a
// per-wave 2KB LDS buffer -> 2x b128/lane fully-coalesced 2KB block store).
// Rationale: WRITE_SIZE = 193MB vs ~119MB clean; the old per-t2 store wrote
// 16x 32B chunks at 128B stride per instruction (partial 64B sectors). r1's
// clean-store layout measured 100MB -> the amp tracks this store pattern.
// LDS swizzle ^((col&7)<<4) keeps write and readback <=2-way (free).
// ---------------------------------------------------------------------------
__global__ void k1_append(
    const float* __restrict__ x, const float* __restrict__ M,
    const float* __restrict__ W, unsigned short* __restrict__ Yt,
    const int* __restrict__ rows, const int* __restrict__ cols,
    const float* __restrict__ vals, int* __restrict__ bcnt,
    i32x2* __restrict__ btmp)
{
    __shared__ __align__(16) char lds[16384];
    __shared__ __align__(16) char ybuf[4][2048];

    if (blockIdx.x < K1BLKS) {
        const int tid  = threadIdx.x;
        const int wid  = tid >> 6;
        const int lane = tid & 63;
        const int col  = lane & 15;   // MFMA m/n index
        const int grp  = lane >> 4;   // MFMA k-group

        // W as B-frags for 16x16x32: lane holds B[k=q*32+grp*8+j][n=t*16+col]
        bf16x8 bw[2][4];
#pragma unroll
        for (int q = 0; q < 2; ++q)
#pragma unroll
            for (int t = 0; t < 4; ++t) {
                U8 w8;
#pragma unroll
                for (int p = 0; p < 4; ++p)
                    w8.u[p] = pack2bf(W[(q*32 + grp*8 + 2*p)*FF + t*16 + col],
                                      W[(q*32 + grp*8 + 2*p + 1)*FF + t*16 + col]);
                bw[q][t] = w8.v;
            }

        // M fragment: element j = M[col][grp*4+j] (B-frag of mix MFMA = M^T)
        U4 m4;
        m4.u[0] = pack2bf(M[col*16 + grp*4 + 0], M[col*16 + grp*4 + 1]);
        m4.u[1] = pack2bf(M[col*16 + grp*4 + 2], M[col*16 + grp*4 + 3]);
        const bf16x4 mf = m4.v;
        const f32x4 zero = {0.f, 0.f, 0.f, 0.f};
        char* yb2 = ybuf[wid];

        // stage: wave stages slices s=wid*4..+3 of an 8-node tile.
        // LDS layout [s][node][fi] bf16, slice stride 1024B, swz ^((s&7)<<4).
#define STAGE(tt)                                                             \
        {                                                                     \
            const int nb_ = (tt)*8;                                           \
            _Pragma("unroll")                                                 \
            for (int q = 0; q < 4; ++q) {                                     \
                const int s_ = wid*4 + q;                                     \
                const float* src_ = x + (size_t)s_*NN*FF + (size_t)nb_*FF + lane*8; \
                float4 lo_ = *reinterpret_cast<const float4*>(src_);          \
                float4 hi_ = *reinterpret_cast<const float4*>(src_ + 4);      \
                U8 pk_;                                                       \
                pk_.u[0] = pack2bf(lo_.x, lo_.y); pk_.u[1] = pack2bf(lo_.z, lo_.w); \
                pk_.u[2] = pack2bf(hi_.x, hi_.y); pk_.u[3] = pack2bf(hi_.z, hi_.w); \
                const int byte_ = (s_*1024 + lane*16) ^ ((s_ & 7) << 4);      \
                *reinterpret_cast<bf16x8*>(lds + byte_) = pk_.v;              \
            }                                                                 \
        }

        const int t0 = blockIdx.x*4;
#pragma unroll
        for (int i = 0; i < 4; ++i) {
            const int t = t0 + i;
            if (t >= NTILES) break;
            STAGE(t)
            __syncthreads();

#pragma unroll
            for (int h = 0; h < 2; ++h) {
                const int nloc = wid*2 + h;
                const int node = t*8 + nloc;
                const int base = col*1024 + nloc*128;
                const int sw = (col & 7) << 4;
                bf16x8 a0 = *reinterpret_cast<const bf16x8*>(lds + ((base + grp*16) ^ sw));
                bf16x8 a1 = *reinterpret_cast<const bf16x8*>(lds + ((base + 64 + grp*16) ^ sw));

                f32x4 acc[4];
#pragma unroll
                for (int t2 = 0; t2 < 4; ++t2) acc[t2] = zero;
#pragma unroll
                for (int t2 = 0; t2 < 4; ++t2)
                    acc[t2] = __builtin_amdgcn_mfma_f32_16x16x32_bf16(a0, bw[0][t2], acc[t2], 0, 0, 0);
#pragma unroll
                for (int t2 = 0; t2 < 4; ++t2)
                    acc[t2] = __builtin_amdgcn_mfma_f32_16x16x32_bf16(a1, bw[1][t2], acc[t2], 0, 0, 0);

                // mix MFMA -> per-wave LDS buffer (logical [k=col][fo] byte
                // col*128 + t2*32 + grp*8, swizzled within the 128B row)
#pragma unroll
                for (int t2 = 0; t2 < 4; ++t2) {
                    U4 pb;
                    pb.u[0] = pack2bf(acc[t2][0], acc[t2][1]);
                    pb.u[1] = pack2bf(acc[t2][2], acc[t2][3]);
                    f32x4 y = mfma16x16x16bf16(pb.v, mf, zero);
                    u32x2 st;
                    st[0] = pack2bf(y[0], y[1]);
                    st[1] = pack2bf(y[2], y[3]);
                    const int lb = col*128 + ((t2*32 + grp*8) ^ ((col & 7) << 4));
                    *reinterpret_cast<u32x2*>(yb2 + lb) = st;
                }
                __builtin_amdgcn_sched_barrier(0);   // LDS writes before readback

                // coalesced 2KB node-block store: lane owns bytes [lane*32, +32)
                {
                    const int lrow  = lane >> 2;                       // logical k row
                    const int loff0 = ((lane & 3)*32) ^ ((lrow & 7) << 4);
                    bf16x8 w0 = *reinterpret_cast<const bf16x8*>(yb2 + lrow*128 + loff0);
                    bf16x8 w1 = *reinterpret_cast<const bf16x8*>(yb2 + lrow*128 + (loff0 ^ 16));
                    char* dst = reinterpret_cast<char*>(Yt + (size_t)node*1024) + lane*32;
                    *reinterpret_cast<bf16x8*>(dst)      = w0;
                    *reinterpret_cast<bf16x8*>(dst + 16) = w1;
                }
                __builtin_amdgcn_sched_barrier(0);   // readback before next h's writes
            }
            __syncthreads();   // before next STAGE overwrites the x-tile
        }
#undef STAGE
    } else {
        // ================= append (1 edge/thread, r18-proven) =================
        const int i = (blockIdx.x - K1BLKS)*256 + threadIdx.x;   // 0..NEDGE-1
        const int r = rows[i];
        const int j = i >> 17;                        // EE = 2^17
        const int b = (r >> 5)*NSUB + (blockIdx.x & 7);
        const int pos = atomicAdd(&bcnt[b], 1);
        if (pos < BCAP) {
            i32x2 e;
            e[0] = cols[i] | (((r & 31)*16 + j) << 16);
            e[1] = __float_as_int(vals[i]);
            btmp[(size_t)b*BCAP + pos] = e;
        }
    }
}

// ---------------------------------------------------------------------------
// sort: block per range. Counting-sort the range's edges in LDS, write back
// IN PLACE (linear, coalesced), sorted by key=(rl,j), + 513-int offset header.
// ---------------------------------------------------------------------------
__global__ __launch_bounds__(256) void sort_kernel(
    const int* __restrict__ bcnt, i32x2* __restrict__ btmp)
{
    __shared__ i32x2 sbuf[SLOTS];     // 16KB
    __shared__ int scnt[512], soff[512], scur[512], pscan[256];

    const int tid = threadIdx.x;
    const int blk = blockIdx.x;
    i32x2* region = btmp + (size_t)blk*SLOTS;

    scnt[tid] = 0; scnt[tid + 256] = 0;
    __syncthreads();

    int bc[NSUB]; i32x2 ent[NSUB];
#pragma unroll
    for (int s = 0; s < NSUB; ++s) {
        int c = bcnt[blk*NSUB + s];
        bc[s] = c < BCAP ? c : BCAP;
    }
#pragma unroll
    for (int s = 0; s < NSUB; ++s)
        if (tid < bc[s]) {
            ent[s] = region[s*BCAP + tid];
            atomicAdd(&scnt[((unsigned)ent[s][0]) >> 16], 1);
        }
    __syncthreads();

    const int a0 = scnt[2*tid], a1 = scnt[2*tid + 1];
    const int ps = a0 + a1;
    pscan[tid] = ps;
    __syncthreads();
    for (int o = 1; o < 256; o <<= 1) {
        int v = (tid >= o) ? pscan[tid - o] : 0;
        __syncthreads();
        pscan[tid] += v;
        __syncthreads();
    }
    const int excl = pscan[tid] - ps;
    soff[2*tid] = excl;      soff[2*tid + 1] = excl + a0;
    scur[2*tid] = excl;      scur[2*tid + 1] = excl + a0;
    __syncthreads();

#pragma unroll
    for (int s = 0; s < NSUB; ++s)
        if (tid < bc[s]) {
            const int key = ((unsigned)ent[s][0]) >> 16;
            const int pos = atomicAdd(&scur[key], 1);
            i32x2 se; se[0] = ent[s][0] & 0xFFFF; se[1] = ent[s][1];
            sbuf[pos] = se;
        }
    __syncthreads();

    const int total = soff[511] + scnt[511];
    const int lim = total < EMAX ? total : EMAX;
    for (int i = tid; i < lim; i += 256) region[i] = sbuf[i];
    int* tail = (int*)region + TAILI;
    tail[tid] = soff[tid];
    tail[tid + 256] = soff[tid + 256];
    if (tid == 0) tail[512] = lim;
}

// ---------------------------------------------------------------------------
// k2_gather: one wave per row (proven ~166us; practical floor per r10/r20
// k-split failures). acc[16], plain loads, single pass. Unchanged.
// ---------------------------------------------------------------------------
template<int J>
__device__ __forceinline__ void k2_batch(int p0, int nj, int sbase, int esub, int fq,
    const i32x2* eb, const unsigned short* __restrict__ Yt,
    const float* __restrict__ M, f32x4* acc)
{
    const int p = p0 + esub;
    const bool act = p < nj;
    const int li = act ? (sbase + p) : 0;
    const i32x2 ent = eb[li];                 // LDS read
    const float v = act ? __int_as_float(ent[1]) : 0.f;
    const int node = act ? ent[0] : 0;        // masked lanes read Yt[0]
    const unsigned short* yb = Yt + (size_t)node*1024 + J*64 + fq*4;
    {
        const u32x2 uv = *reinterpret_cast<const u32x2*>(yb);
        const float wv = M[J*17] * v;
        acc[J][0] = fmaf(wv, lo16f(uv[0]), acc[J][0]);
        acc[J][1] = fmaf(wv, hi16f(uv[0]), acc[J][1]);
        acc[J][2] = fmaf(wv, lo16f(uv[1]), acc[J][2]);
        acc[J][3] = fmaf(wv, hi16f(uv[1]), acc[J][3]);
    }
    if constexpr (J < 15) {
        const u32x2 uv = *reinterpret_cast<const u32x2*>(yb + 64);
        const float wv = M[J*17 + 16] * v;
        acc[J+1][0] = fmaf(wv, lo16f(uv[0]), acc[J+1][0]);
        acc[J+1][1] = fmaf(wv, hi16f(uv[0]), acc[J+1][1]);
        acc[J+1][2] = fmaf(wv, lo16f(uv[1]), acc[J+1][2]);
        acc[J+1][3] = fmaf(wv, hi16f(uv[1]), acc[J+1][3]);
    }
    if constexpr (J < 14) {
        const u32x2 uv = *reinterpret_cast<const u32x2*>(yb + 128);
        const float wv = M[J*17 + 32] * v;
        acc[J+2][0] = fmaf(wv, lo16f(uv[0]), acc[J+2][0]);
        acc[J+2][1] = fmaf(wv, hi16f(uv[0]), acc[J+2][1]);
        acc[J+2][2] = fmaf(wv, lo16f(uv[1]), acc[J+2][2]);
        acc[J+2][3] = fmaf(wv, hi16f(uv[1]), acc[J+2][3]);
    }
}

__global__ __launch_bounds__(256) void k2_gather(
    const unsigned short* __restrict__ Yt, const float* __restrict__ M,
    const i32x2* __restrict__ btmp, float* __restrict__ out)
{
    __shared__ i32x2 ebuf[4][128];
    const int tid  = threadIdx.x;
    const int wid  = tid >> 6;
    const int lane = tid & 63;
    const int esub = lane >> 4;   // edge slot 0..3
    const int fq   = lane & 15;   // feature quad
    const int r   = blockIdx.x*4 + wid;   // 12500*4 = 50000 exact
    const int blk = r >> 5;
    const int rl  = r & 31;

    const i32x2* region = btmp + (size_t)blk*SLOTS;
    const int* tail = (const int*)region + TAILI;
    int o_l = 0;
    if (lane < 17) o_l = tail[rl*16 + lane];
    int off[17];
#pragma unroll
    for (int j = 0; j < 17; ++j) off[j] = __builtin_amdgcn_readlane(o_l, j);
    int ntot = off[16] - off[0];
    ntot = ntot < 128 ? ntot : 128;
    const i32x2* rowsrc = region + off[0];

    i32x2* eb = ebuf[wid];
    if (lane < ntot)      eb[lane]      = rowsrc[lane];
    if (lane + 64 < ntot) eb[lane + 64] = rowsrc[lane + 64];

    int c[16], sb[16];
#pragma unroll
    for (int j = 0; j < 16; ++j) {
        c[j]  = off[j+1] - off[j];
        sb[j] = off[j] - off[0];
    }

    f32x4 acc[16];
#pragma unroll
    for (int k = 0; k < 16; ++k) acc[k] = (f32x4){0.f, 0.f, 0.f, 0.f};

    // pass 1: first batch of every section, straight-line
#define P1(J) k2_batch<J>(0, c[J], sb[J], esub, fq, eb, Yt, M, acc);
    P1(0)  P1(1)  P1(2)  P1(3)  P1(4)  P1(5)  P1(6)  P1(7)
    P1(8)  P1(9)  P1(10) P1(11) P1(12) P1(13) P1(14) P1(15)
#undef P1
    // pass 2: residual batches (usually empty)
#define P2(J) for (int p0 = 4; p0 < c[J]; p0 += 4) \
        k2_batch<J>(p0, c[J], sb[J], esub, fq, eb, Yt, M, acc);
    P2(0)  P2(1)  P2(2)  P2(3)  P2(4)  P2(5)  P2(6)  P2(7)
    P2(8)  P2(9)  P2(10) P2(11) P2(12) P2(13) P2(14) P2(15)
#undef P2

#pragma unroll
    for (int k = 0; k < 16; ++k) {
#pragma unroll
        for (int u = 0; u < 4; ++u) {
            acc[k][u] += __shfl_xor(acc[k][u], 16);
            acc[k][u] += __shfl_xor(acc[k][u], 32);
        }
    }
    if (esub == 0) {
#pragma unroll
        for (int k = 0; k < 16; ++k) {
            *reinterpret_cast<f32x4*>(out + ((size_t)k*NN + r)*FF + fq*4) = acc[k];
        }
    }
}

// ---------------------------------------------------------------------------
extern "C" void kernel_launch(void* const* d_in, const int* in_sizes, int n_in,
                              void* d_out, int out_size, void* d_ws, size_t ws_size,
                              hipStream_t stream) {
    (void)in_sizes; (void)n_in; (void)out_size; (void)ws_size;
    const float* x     = (const float*)d_in[0];
    const float* M     = (const float*)d_in[1];
    const float* avals = (const float*)d_in[2];
    const float* W     = (const float*)d_in[3];
    const int*   arows = (const int*)d_in[4];
    const int*   acols = (const int*)d_in[5];
    float* out = (float*)d_out;

    // workspace carve (~128.1 MB total)
    char* ws = (char*)d_ws;
    size_t o = 0;
    unsigned short* Yt = (unsigned short*)(ws + o); o += (size_t)TT*NN*FF*2;  // 102.4 MB
    o = (o + 255) & ~(size_t)255;
    int* bcnt = (int*)(ws + o); o += (size_t)NBUCK*4;  o = (o + 255) & ~(size_t)255;
    i32x2* btmp = (i32x2*)(ws + o);                    // 12504*2048*8 = 25.6 MB

    (void)hipMemsetAsync(bcnt, 0, (size_t)NBUCK*4, stream);
    hipLaunchKernelGGL(k1_append, dim3(K1BLKS + APPBLKS), dim3(256), 0, stream,
                       x, M, W, Yt, arows, acols, avals, bcnt, btmp);
    hipLaunchKernelGGL(sort_kernel, dim3(NRANGE), dim3(256), 0, stream, bcnt, btmp);
    hipLaunchKernelGGL(k2_gather, dim3(12500), dim3(256), 0, stream, Yt, M, btmp, out);
}